// Round 1
// baseline (1290.103 us; speedup 1.0000x reference)
//
#include <hip/hip_runtime.h>
#include <math.h>

#define BB 32768
#define DD 512
#define CC 527
#define CPAD 576   // 9 * 64 column groups
#define TM 32      // rows per block
#define KT 16      // k-tile
#define NB 128     // histogram bins
#define CAP 64     // candidate capacity per row
#define WST 20     // LDS W-tile row stride in floats (16 + 4 pad, keeps 16B align, bank-uniform)

struct SMemG {
  float xs[TM][KT];      // 2 KB
  float ws[CPAD][WST];   // 46 KB
};
struct SMemE {
  int   hist[TM][NB];    // 16 KB
  float cand[TM][CAP];   // 8 KB
  int   candn[TM];
  int   kcnt[TM];
  int   bsel[TM];
  int   chi[TM];
  float tval[TM];
  int   ties[TM];
  int   hits[TM];
  int   eqp[TM];
  float red[4];
  float scorered;
};
union SMemU { SMemG g; SMemE e; };

__device__ __forceinline__ int bin_of(float z) {
  int b = (int)floorf((z + 4.0f) * 16.0f);   // 128 bins over [-4, 4]
  return min(max(b, 0), NB - 1);
}

__global__ __launch_bounds__(256, 2)
void fused_bce_topk(const float* __restrict__ x, const float* __restrict__ y,
                    const float* __restrict__ W, const float* __restrict__ bias,
                    const float* __restrict__ pw, float* __restrict__ accum) {
  __shared__ SMemU sm;
  const int tid = threadIdx.x;
  const int ct  = tid & 63;   // column thread 0..63
  const int rt  = tid >> 6;   // row group 0..3
  const int r0  = blockIdx.x * TM;

  float acc[8][9];
#pragma unroll
  for (int r = 0; r < 8; ++r)
#pragma unroll
    for (int j = 0; j < 9; ++j) acc[r][j] = 0.f;

  // ---------------- GEMM: logits tile [32 x 527] over K=512 ----------------
  for (int k0 = 0; k0 < DD; k0 += KT) {
    if (tid < 128) {
      int r = tid >> 2, q = tid & 3;
      float4 v = *(const float4*)(x + (size_t)(r0 + r) * DD + k0 + q * 4);
      *(float4*)(&sm.g.xs[r][q * 4]) = v;
    }
    for (int idx = tid; idx < CPAD * 4; idx += 256) {
      int c = idx >> 2, q = idx & 3;
      float4 v = make_float4(0.f, 0.f, 0.f, 0.f);
      if (c < CC) v = *(const float4*)(W + (size_t)c * DD + k0 + q * 4);
      *(float4*)(&sm.g.ws[c][q * 4]) = v;
    }
    __syncthreads();
#pragma unroll
    for (int q = 0; q < KT / 4; ++q) {
      float4 xv[8], wv[9];
#pragma unroll
      for (int r = 0; r < 8; ++r) xv[r] = *(const float4*)(&sm.g.xs[rt * 8 + r][q * 4]);
#pragma unroll
      for (int j = 0; j < 9; ++j) wv[j] = *(const float4*)(&sm.g.ws[ct + 64 * j][q * 4]);
#pragma unroll
      for (int r = 0; r < 8; ++r)
#pragma unroll
        for (int j = 0; j < 9; ++j) {
          acc[r][j] = fmaf(xv[r].x, wv[j].x, acc[r][j]);
          acc[r][j] = fmaf(xv[r].y, wv[j].y, acc[r][j]);
          acc[r][j] = fmaf(xv[r].z, wv[j].z, acc[r][j]);
          acc[r][j] = fmaf(xv[r].w, wv[j].w, acc[r][j]);
        }
    }
    __syncthreads();
  }

  // ---------------- Epilogue (LDS union reuse) ----------------
  for (int i = tid; i < TM * NB; i += 256) ((int*)sm.e.hist)[i] = 0;
  if (tid < TM) {
    sm.e.candn[tid] = 0; sm.e.kcnt[tid] = 0;
    sm.e.hits[tid] = 0;  sm.e.eqp[tid] = 0;
  }
  if (tid == 0) sm.e.scorered = 0.f;
  __syncthreads();

  float bv[9], pv[9];
#pragma unroll
  for (int j = 0; j < 9; ++j) {
    int c = ct + 64 * j;
    bv[j] = (c < CC) ? bias[c] : 0.f;
    pv[j] = (c < CC) ? pw[c]   : 1.f;
  }

  // Pass 1: z = acc + b, loss terms, positive mask, per-row k count, histogram.
  float lossloc = 0.f;
  unsigned short ym[8];
#pragma unroll
  for (int r = 0; r < 8; ++r) {
    const int row = rt * 8 + r;
    int kloc = 0; ym[r] = 0;
#pragma unroll
    for (int j = 0; j < 9; ++j) {
      int c = ct + 64 * j;
      if (c < CC) {
        float z = acc[r][j] + bv[j];
        acc[r][j] = z;
        float yv = y[(size_t)(r0 + row) * CC + c];
        float a  = fabsf(z);
        float l1 = log1pf(__expf(-a));
        float sp_pos = fmaxf(z, 0.f) + l1;   // softplus(z)  = -log_sigmoid(-z)
        float sp_neg = sp_pos - z;           // softplus(-z) = -log_sigmoid(z)
        lossloc += pv[j] * yv * sp_neg + (1.f - yv) * sp_pos;
        if (yv > 0.5f) { ym[r] |= (unsigned short)(1u << j); ++kloc; }
        atomicAdd(&sm.e.hist[row][bin_of(z)], 1);
      }
    }
    if (kloc) atomicAdd(&sm.e.kcnt[row], kloc);
  }
  __syncthreads();

  // Pass 2: suffix-scan histogram -> bin containing the k-th largest logit.
  if (tid < TM) {
    int k = sm.e.kcnt[tid];          // >= 1 guaranteed (y[:,0] = 1)
    int cum = 0, b = NB - 1;
    for (; b >= 0; --b) {
      int h = sm.e.hist[tid][b];
      if (cum + h >= k) break;
      cum += h;
    }
    sm.e.bsel[tid] = b;
    sm.e.chi[tid]  = cum;            // count strictly in higher bins
  }
  __syncthreads();

  // Pass 3: collect candidates in selected bin.
#pragma unroll
  for (int r = 0; r < 8; ++r) {
    const int row = rt * 8 + r;
    const int bs = sm.e.bsel[row];
#pragma unroll
    for (int j = 0; j < 9; ++j) {
      int c = ct + 64 * j;
      if (c < CC) {
        float z = acc[r][j];
        if (bin_of(z) == bs) {
          int p = atomicAdd(&sm.e.candn[row], 1);
          if (p < CAP) sm.e.cand[row][p] = z;
        }
      }
    }
  }
  __syncthreads();

  // Pass 4: exact k-th largest within the bin (tiny destructive select).
  if (tid < TM) {
    int m  = min(sm.e.candn[tid], CAP);
    int kk = sm.e.kcnt[tid] - sm.e.chi[tid];  // rank within bin, >= 1
    if (kk > m) kk = m;                        // unreachable safety
    float t = -3.4e38f; int eqext = 0;
    for (int it = 0; it < kk; ++it) {
      float bvv = -3.4e38f; int bi = 0;
      for (int i = 0; i < m; ++i) {
        float v = sm.e.cand[tid][i];
        if (v > bvv) { bvv = v; bi = i; }
      }
      if (bvv == t) ++eqext; else { t = bvv; eqext = 1; }
      sm.e.cand[tid][bi] = -3.4e38f;
    }
    sm.e.tval[tid] = t;
    sm.e.ties[tid] = eqext;  // number of values == t that are inside top-k
  }
  __syncthreads();

  // Pass 5: hits among positives.
#pragma unroll
  for (int r = 0; r < 8; ++r) {
    const int row = rt * 8 + r;
    const float t = sm.e.tval[row];
    int h = 0, e = 0;
#pragma unroll
    for (int j = 0; j < 9; ++j) {
      if ((ym[r] >> j) & 1) {
        float z = acc[r][j];
        if (z > t) ++h;
        else if (z == t) ++e;
      }
    }
    if (h) atomicAdd(&sm.e.hits[row], h);
    if (e) atomicAdd(&sm.e.eqp[row], e);
  }
  __syncthreads();

  // Per-row score, block reductions, one global atomic per block per output.
  if (tid < TM) {
    int k = sm.e.kcnt[tid];
    int hits = sm.e.hits[tid] + min(sm.e.eqp[tid], sm.e.ties[tid]);
    atomicAdd(&sm.e.scorered, (float)hits / (float)k);
  }
  float l = lossloc;
#pragma unroll
  for (int off = 32; off > 0; off >>= 1) l += __shfl_down(l, off, 64);
  if ((tid & 63) == 0) sm.e.red[tid >> 6] = l;
  __syncthreads();
  if (tid == 0) {
    atomicAdd(&accum[0], sm.e.red[0] + sm.e.red[1] + sm.e.red[2] + sm.e.red[3]);
    atomicAdd(&accum[1], sm.e.scorered);
  }
}

__global__ void init_ws_kernel(float* ws) {
  ws[0] = 0.f;
  ws[1] = 0.f;
}

__global__ void finalize_kernel(const float* __restrict__ ws, float* __restrict__ out) {
  out[0] = (float)((double)ws[0] / ((double)BB * (double)CC));
  out[1] = (float)((double)ws[1] / (double)BB);
}

extern "C" void kernel_launch(void* const* d_in, const int* in_sizes, int n_in,
                              void* d_out, int out_size, void* d_ws, size_t ws_size,
                              hipStream_t stream) {
  const float* x  = (const float*)d_in[0];
  const float* y  = (const float*)d_in[1];
  const float* W  = (const float*)d_in[2];
  const float* b  = (const float*)d_in[3];
  const float* pw = (const float*)d_in[4];
  float* out = (float*)d_out;
  float* ws  = (float*)d_ws;

  hipLaunchKernelGGL(init_ws_kernel, dim3(1), dim3(1), 0, stream, ws);
  hipLaunchKernelGGL(fused_bce_topk, dim3(BB / TM), dim3(256), 0, stream,
                     x, y, W, b, pw, ws);
  hipLaunchKernelGGL(finalize_kernel, dim3(1), dim3(1), 0, stream, ws, out);
}

// Round 2
// 662.550 us; speedup vs baseline: 1.9472x; 1.9472x over previous
//
#include <hip/hip_runtime.h>
#include <math.h>

#define BB 32768
#define DD 512
#define CC 527
#define NT 34      // 34 n-tiles of 16 -> 544 padded cols
#define BM 64      // rows per block (4 waves x 16)
#define BK 32      // k-tile (one mfma K)
#define LDA 40     // LDS row stride in bf16 elements (80B) -> conflict-free b128

typedef __attribute__((ext_vector_type(8))) short bf16x8;
typedef __attribute__((ext_vector_type(4))) float f32x4;

__device__ __forceinline__ short f2bf(float f) {  // fp32 -> bf16 RNE
  unsigned u = __float_as_uint(f);
  u += 0x7fffu + ((u >> 16) & 1u);
  return (short)(u >> 16);
}

__global__ __launch_bounds__(256, 2)
void fused_mfma_bce_topk(const float* __restrict__ x, const float* __restrict__ y,
                         const float* __restrict__ W, const float* __restrict__ bias,
                         const float* __restrict__ pw, float* __restrict__ accum) {
  __shared__ short As[BM * LDA];      // 5.0 KB
  __shared__ short Bs[544 * LDA];     // 42.5 KB
  __shared__ float redL[4], redS[4];

  const int tid  = threadIdx.x;
  const int wave = tid >> 6;
  const int lane = tid & 63;
  const int cl   = lane & 15;   // col within 16-tile / frag row index
  const int quad = lane >> 4;   // k-chunk (operands) / row-group (C/D)
  const int r0   = blockIdx.x * BM;

  f32x4 acc[NT];
#pragma unroll
  for (int t = 0; t < NT; ++t) acc[t] = (f32x4){0.f, 0.f, 0.f, 0.f};

  const int arow = tid >> 2, apos = tid & 3;

  // ---------------- MFMA GEMM over K = 512 ----------------
  for (int k0 = 0; k0 < DD; k0 += BK) {
    // Stage A: x[r0 .. r0+63][k0 .. k0+31] fp32 -> bf16
    {
      const float* s = x + (size_t)(r0 + arow) * DD + k0 + apos * 8;
      float4 f0 = *(const float4*)s;
      float4 f1 = *(const float4*)(s + 4);
      bf16x8 v;
      v[0]=f2bf(f0.x); v[1]=f2bf(f0.y); v[2]=f2bf(f0.z); v[3]=f2bf(f0.w);
      v[4]=f2bf(f1.x); v[5]=f2bf(f1.y); v[6]=f2bf(f1.z); v[7]=f2bf(f1.w);
      *(bf16x8*)(&As[arow * LDA + apos * 8]) = v;
    }
    // Stage B: W[0..526][k0..k0+31] fp32 -> bf16 (rows 527..543 zero)
#pragma unroll
    for (int i = 0; i < 9; ++i) {
      int ch = tid + i * 256;
      if (ch < 544 * 4) {
        int row = ch >> 2, pos = ch & 3;
        short zz = 0;
        bf16x8 v = {zz, zz, zz, zz, zz, zz, zz, zz};
        if (row < CC) {
          const float* s = W + (size_t)row * DD + k0 + pos * 8;
          float4 f0 = *(const float4*)s;
          float4 f1 = *(const float4*)(s + 4);
          v[0]=f2bf(f0.x); v[1]=f2bf(f0.y); v[2]=f2bf(f0.z); v[3]=f2bf(f0.w);
          v[4]=f2bf(f1.x); v[5]=f2bf(f1.y); v[6]=f2bf(f1.z); v[7]=f2bf(f1.w);
        }
        *(bf16x8*)(&Bs[row * LDA + pos * 8]) = v;
      }
    }
    __syncthreads();
    // A-frag: lane holds A[m=cl][k = quad*8 + j]
    bf16x8 af = *(const bf16x8*)(&As[(wave * 16 + cl) * LDA + quad * 8]);
#pragma unroll
    for (int t = 0; t < NT; ++t) {
      bf16x8 bf = *(const bf16x8*)(&Bs[(t * 16 + cl) * LDA + quad * 8]);
      acc[t] = __builtin_amdgcn_mfma_f32_16x16x32_bf16(af, bf, acc[t], 0, 0, 0);
    }
    __syncthreads();
  }

  // ---------------- Epilogue (fragment-native, atomic-free) ----------------
  // C/D layout: col = t*16 + cl, row (within wave tile) = quad*4 + r
  const size_t growbase = (size_t)(r0 + wave * 16 + quad * 4);
  float lossloc = 0.f;
  unsigned long long ym[4] = {0ull, 0ull, 0ull, 0ull};

#pragma unroll
  for (int t = 0; t < NT; ++t) {
    int col = t * 16 + cl;
    bool cv = (col < CC);
    float bt = cv ? bias[col] : 0.f;
    float pt = cv ? pw[col]   : 1.f;
#pragma unroll
    for (int r = 0; r < 4; ++r) {
      float z = acc[t][r] + bt;
      if (cv) {
        float yv = y[(growbase + r) * CC + col];
        float a  = fabsf(z);
        float l1 = log1pf(__expf(-a));
        float sp_pos = fmaxf(z, 0.f) + l1;   // softplus(z)
        float sp_neg = sp_pos - z;           // softplus(-z)
        lossloc += pt * yv * sp_neg + (1.f - yv) * sp_pos;
        if (yv > 0.5f) ym[r] |= (1ull << t);
        acc[t][r] = z;
      } else {
        acc[t][r] = -1e30f;   // exclude pad cols from ranking
      }
    }
  }

  // k per row: popcount + 16-lane (quad) butterfly reduce, 2 rows packed/u32
  unsigned pk01 = (unsigned)__popcll(ym[0]) | ((unsigned)__popcll(ym[1]) << 16);
  unsigned pk23 = (unsigned)__popcll(ym[2]) | ((unsigned)__popcll(ym[3]) << 16);
#pragma unroll
  for (int m = 1; m <= 8; m <<= 1) {
    pk01 += __shfl_xor(pk01, m, 64);
    pk23 += __shfl_xor(pk23, m, 64);
  }
  const int kr[4] = {(int)(pk01 & 0xffffu), (int)(pk01 >> 16),
                     (int)(pk23 & 0xffffu), (int)(pk23 >> 16)};

  // Bisection for per-row threshold th with |{z > th}| == k (exact, no ties in data)
  float lo[4], hi[4], th[4];
  bool fnd[4];
#pragma unroll
  for (int r = 0; r < 4; ++r) { lo[r] = -1024.f; hi[r] = 1024.f; th[r] = 0.f; fnd[r] = false; }

  for (int it = 0; it < 48; ++it) {
    float tm[4];
#pragma unroll
    for (int r = 0; r < 4; ++r) tm[r] = 0.5f * (lo[r] + hi[r]);
    int c[4] = {0, 0, 0, 0};
#pragma unroll
    for (int t = 0; t < NT; ++t)
#pragma unroll
      for (int r = 0; r < 4; ++r) c[r] += (acc[t][r] > tm[r]) ? 1 : 0;
    unsigned p01 = (unsigned)c[0] | ((unsigned)c[1] << 16);
    unsigned p23 = (unsigned)c[2] | ((unsigned)c[3] << 16);
#pragma unroll
    for (int m = 1; m <= 8; m <<= 1) {
      p01 += __shfl_xor(p01, m, 64);
      p23 += __shfl_xor(p23, m, 64);
    }
    const int cc4[4] = {(int)(p01 & 0xffffu), (int)(p01 >> 16),
                        (int)(p23 & 0xffffu), (int)(p23 >> 16)};
    bool rem = false;
#pragma unroll
    for (int r = 0; r < 4; ++r) {
      if (!fnd[r]) {
        if (cc4[r] == kr[r])                        { th[r] = tm[r]; fnd[r] = true; }
        else if (tm[r] <= lo[r] || tm[r] >= hi[r])  { th[r] = lo[r]; fnd[r] = true; } // precision exhausted (ties)
        else if (cc4[r] > kr[r])                    lo[r] = tm[r];
        else                                        hi[r] = tm[r];
      }
      rem |= !fnd[r];
    }
    if (__ballot(rem) == 0ull) break;
  }

  // hits = positives strictly above threshold
  int h[4] = {0, 0, 0, 0};
#pragma unroll
  for (int t = 0; t < NT; ++t)
#pragma unroll
    for (int r = 0; r < 4; ++r)
      if (((ym[r] >> t) & 1ull) && acc[t][r] > th[r]) h[r]++;
  unsigned q01 = (unsigned)h[0] | ((unsigned)h[1] << 16);
  unsigned q23 = (unsigned)h[2] | ((unsigned)h[3] << 16);
#pragma unroll
  for (int m = 1; m <= 8; m <<= 1) {
    q01 += __shfl_xor(q01, m, 64);
    q23 += __shfl_xor(q23, m, 64);
  }
  float scoreloc = 0.f;
  if (cl == 0) {
    const int hh[4] = {(int)(q01 & 0xffffu), (int)(q01 >> 16),
                       (int)(q23 & 0xffffu), (int)(q23 >> 16)};
#pragma unroll
    for (int r = 0; r < 4; ++r) scoreloc += (float)hh[r] / (float)kr[r];
  }

  // Block reduction -> one global atomic per block per output
#pragma unroll
  for (int m = 1; m < 64; m <<= 1) {
    lossloc  += __shfl_xor(lossloc, m, 64);
    scoreloc += __shfl_xor(scoreloc, m, 64);
  }
  if (lane == 0) { redL[wave] = lossloc; redS[wave] = scoreloc; }
  __syncthreads();
  if (tid == 0) {
    atomicAdd(&accum[0], redL[0] + redL[1] + redL[2] + redL[3]);
    atomicAdd(&accum[1], redS[0] + redS[1] + redS[2] + redS[3]);
  }
}

__global__ void init_ws_kernel(float* ws) {
  ws[0] = 0.f;
  ws[1] = 0.f;
}

__global__ void finalize_kernel(const float* __restrict__ ws, float* __restrict__ out) {
  out[0] = (float)((double)ws[0] / ((double)BB * (double)CC));
  out[1] = (float)((double)ws[1] / (double)BB);
}

extern "C" void kernel_launch(void* const* d_in, const int* in_sizes, int n_in,
                              void* d_out, int out_size, void* d_ws, size_t ws_size,
                              hipStream_t stream) {
  const float* x  = (const float*)d_in[0];
  const float* y  = (const float*)d_in[1];
  const float* W  = (const float*)d_in[2];
  const float* b  = (const float*)d_in[3];
  const float* pw = (const float*)d_in[4];
  float* out = (float*)d_out;
  float* ws  = (float*)d_ws;

  hipLaunchKernelGGL(init_ws_kernel, dim3(1), dim3(1), 0, stream, ws);
  hipLaunchKernelGGL(fused_mfma_bce_topk, dim3(BB / BM), dim3(256), 0, stream,
                     x, y, W, b, pw, ws);
  hipLaunchKernelGGL(finalize_kernel, dim3(1), dim3(1), 0, stream, ws, out);
}

// Round 3
// 653.302 us; speedup vs baseline: 1.9747x; 1.0142x over previous
//
#include <hip/hip_runtime.h>
#include <math.h>

#define BB 32768
#define DD 512
#define CC 527
#define NT 33      // 33 n-tiles of 16 -> 528 padded cols (>= 527)
#define NCOL 528
#define BM 64      // rows per block (4 waves x 16 rows)
#define BK 32      // k-tile (one mfma K)
#define LDA 40     // LDS row stride in bf16 elems (80B) -> near-conflict-free b128

typedef __attribute__((ext_vector_type(8))) short bf16x8;
typedef __attribute__((ext_vector_type(4))) float f32x4;

__device__ __forceinline__ short f2bf(float f) {  // fp32 -> bf16 RNE
  unsigned u = __float_as_uint(f);
  u += 0x7fffu + ((u >> 16) & 1u);
  return (short)(u >> 16);
}

__device__ __forceinline__ bf16x8 pack8(const float4& f0, const float4& f1) {
  bf16x8 v;
  v[0] = f2bf(f0.x); v[1] = f2bf(f0.y); v[2] = f2bf(f0.z); v[3] = f2bf(f0.w);
  v[4] = f2bf(f1.x); v[5] = f2bf(f1.y); v[6] = f2bf(f1.z); v[7] = f2bf(f1.w);
  return v;
}

__global__ __launch_bounds__(256, 1)
void fused_mfma_bce_topk(const float* __restrict__ x, const float* __restrict__ y,
                         const float* __restrict__ W, const float* __restrict__ bias,
                         const float* __restrict__ pw, float* __restrict__ accum) {
  __shared__ short As[BM * LDA];        // 5.0 KB
  __shared__ short Bs[NCOL * LDA];      // 41.25 KB
  __shared__ float redL[4], redS[4];

  const int tid  = threadIdx.x;
  const int wave = tid >> 6;
  const int lane = tid & 63;
  const int cl   = lane & 15;
  const int quad = lane >> 4;
  const int r0   = blockIdx.x * BM;

  const int arow = tid >> 2, apos = tid & 3;           // A staging map
  const int brow0 = tid >> 2, bpos = tid & 3;          // B chunk 0 map

  f32x4 acc[NT];
#pragma unroll
  for (int t = 0; t < NT; ++t) acc[t] = (f32x4){0.f, 0.f, 0.f, 0.f};

  // -------- software-pipelined MFMA GEMM over K = 512 --------
  float4 a0A, a1A, b0A[9], b1A[9];     // prefetch set A
  float4 a0B, a1B, b0B[9], b1B[9];     // prefetch set B

#define LOAD_SET(k0, a0, a1, b0, b1)                                          \
  {                                                                           \
    const float* sA = x + (size_t)(r0 + arow) * DD + (k0) + apos * 8;         \
    a0 = *(const float4*)sA; a1 = *(const float4*)(sA + 4);                   \
    _Pragma("unroll")                                                         \
    for (int i = 0; i < 9; ++i) {                                             \
      int ch = tid + i * 256;                                                 \
      if (ch < NCOL * 4) {                                                    \
        int row = ch >> 2, pos = ch & 3;                                      \
        if (row < CC) {                                                       \
          const float* sB = W + (size_t)row * DD + (k0) + pos * 8;            \
          b0[i] = *(const float4*)sB; b1[i] = *(const float4*)(sB + 4);       \
        } else {                                                              \
          b0[i] = make_float4(0.f, 0.f, 0.f, 0.f);                            \
          b1[i] = make_float4(0.f, 0.f, 0.f, 0.f);                            \
        }                                                                     \
      }                                                                       \
    }                                                                         \
  }

#define STORE_SET(a0, a1, b0, b1)                                             \
  {                                                                           \
    *(bf16x8*)(&As[arow * LDA + apos * 8]) = pack8(a0, a1);                   \
    _Pragma("unroll")                                                         \
    for (int i = 0; i < 9; ++i) {                                             \
      int ch = tid + i * 256;                                                 \
      if (ch < NCOL * 4) {                                                    \
        int row = ch >> 2, pos = ch & 3;                                      \
        *(bf16x8*)(&Bs[row * LDA + pos * 8]) = pack8(b0[i], b1[i]);           \
      }                                                                       \
    }                                                                         \
  }

#define COMPUTE()                                                             \
  {                                                                           \
    bf16x8 af = *(const bf16x8*)(&As[(wave * 16 + cl) * LDA + quad * 8]);     \
    _Pragma("unroll")                                                         \
    for (int t = 0; t < NT; ++t) {                                            \
      bf16x8 bfr = *(const bf16x8*)(&Bs[(t * 16 + cl) * LDA + quad * 8]);     \
      acc[t] = __builtin_amdgcn_mfma_f32_16x16x32_bf16(af, bfr, acc[t], 0, 0, 0); \
    }                                                                         \
  }

  LOAD_SET(0, a0A, a1A, b0A, b1A);
#pragma unroll 1
  for (int kt = 0; kt < 16; kt += 2) {
    STORE_SET(a0A, a1A, b0A, b1A);
    __syncthreads();
    LOAD_SET((kt + 1) * BK, a0B, a1B, b0B, b1B);   // prefetch next while computing
    COMPUTE();
    __syncthreads();
    STORE_SET(a0B, a1B, b0B, b1B);
    __syncthreads();
    if (kt + 2 < 16) LOAD_SET((kt + 2) * BK, a0A, a1A, b0A, b1A);
    COMPUTE();
    __syncthreads();
  }
#undef LOAD_SET
#undef STORE_SET
#undef COMPUTE

  // ---------------- Epilogue (fragment-native, atomic-free) ----------------
  // C/D layout: col = t*16 + cl, row (within wave tile) = quad*4 + r
  const size_t growbase = (size_t)(r0 + wave * 16 + quad * 4);
  float lossloc = 0.f;
  unsigned long long ym[4] = {0ull, 0ull, 0ull, 0ull};

#pragma unroll
  for (int t = 0; t < NT; ++t) {
    int col = t * 16 + cl;
    bool cv = (col < CC);
    float bt = cv ? bias[col] : 0.f;
    float pt = cv ? pw[col]   : 1.f;
#pragma unroll
    for (int r = 0; r < 4; ++r) {
      float z = acc[t][r] + bt;
      if (cv) {
        float yv = y[(growbase + r) * CC + col];
        float a  = fabsf(z);
        float l1 = log1pf(__expf(-a));
        float sp_pos = fmaxf(z, 0.f) + l1;   // softplus(z)
        float sp_neg = sp_pos - z;           // softplus(-z)
        lossloc += pt * yv * sp_neg + (1.f - yv) * sp_pos;
        if (yv > 0.5f) ym[r] |= (1ull << t);
        acc[t][r] = z;
      } else {
        acc[t][r] = -1e30f;   // exclude pad col from ranking
      }
    }
  }

  // k per row: popcount + 16-lane butterfly reduce, 2 rows packed per u32
  unsigned pk01 = (unsigned)__popcll(ym[0]) | ((unsigned)__popcll(ym[1]) << 16);
  unsigned pk23 = (unsigned)__popcll(ym[2]) | ((unsigned)__popcll(ym[3]) << 16);
#pragma unroll
  for (int m = 1; m <= 8; m <<= 1) {
    pk01 += __shfl_xor(pk01, m, 64);
    pk23 += __shfl_xor(pk23, m, 64);
  }
  const int kr[4] = {(int)(pk01 & 0xffffu), (int)(pk01 >> 16),
                     (int)(pk23 & 0xffffu), (int)(pk23 >> 16)};

  // Bisection: per-row threshold th with |{z > th}| == k
  float lo[4], hi[4], th[4];
  bool fnd[4];
#pragma unroll
  for (int r = 0; r < 4; ++r) { lo[r] = -1024.f; hi[r] = 1024.f; th[r] = 0.f; fnd[r] = false; }

  for (int it = 0; it < 48; ++it) {
    float tm[4];
#pragma unroll
    for (int r = 0; r < 4; ++r) tm[r] = 0.5f * (lo[r] + hi[r]);
    int c[4] = {0, 0, 0, 0};
#pragma unroll
    for (int t = 0; t < NT; ++t)
#pragma unroll
      for (int r = 0; r < 4; ++r) c[r] += (acc[t][r] > tm[r]) ? 1 : 0;
    unsigned p01 = (unsigned)c[0] | ((unsigned)c[1] << 16);
    unsigned p23 = (unsigned)c[2] | ((unsigned)c[3] << 16);
#pragma unroll
    for (int m = 1; m <= 8; m <<= 1) {
      p01 += __shfl_xor(p01, m, 64);
      p23 += __shfl_xor(p23, m, 64);
    }
    const int cc4[4] = {(int)(p01 & 0xffffu), (int)(p01 >> 16),
                        (int)(p23 & 0xffffu), (int)(p23 >> 16)};
    bool rem = false;
#pragma unroll
    for (int r = 0; r < 4; ++r) {
      if (!fnd[r]) {
        if (cc4[r] == kr[r])                        { th[r] = tm[r]; fnd[r] = true; }
        else if (tm[r] <= lo[r] || tm[r] >= hi[r])  { th[r] = lo[r]; fnd[r] = true; }
        else if (cc4[r] > kr[r])                    lo[r] = tm[r];
        else                                        hi[r] = tm[r];
      }
      rem |= !fnd[r];
    }
    if (__ballot(rem) == 0ull) break;
  }

  // hits = positives strictly above threshold
  int h[4] = {0, 0, 0, 0};
#pragma unroll
  for (int t = 0; t < NT; ++t)
#pragma unroll
    for (int r = 0; r < 4; ++r)
      if (((ym[r] >> t) & 1ull) && acc[t][r] > th[r]) h[r]++;
  unsigned q01 = (unsigned)h[0] | ((unsigned)h[1] << 16);
  unsigned q23 = (unsigned)h[2] | ((unsigned)h[3] << 16);
#pragma unroll
  for (int m = 1; m <= 8; m <<= 1) {
    q01 += __shfl_xor(q01, m, 64);
    q23 += __shfl_xor(q23, m, 64);
  }
  float scoreloc = 0.f;
  if (cl == 0) {
    const int hh[4] = {(int)(q01 & 0xffffu), (int)(q01 >> 16),
                       (int)(q23 & 0xffffu), (int)(q23 >> 16)};
#pragma unroll
    for (int r = 0; r < 4; ++r) scoreloc += (float)hh[r] / (float)kr[r];
  }

  // Block reduction -> one global atomic per block per output
#pragma unroll
  for (int m = 1; m < 64; m <<= 1) {
    lossloc  += __shfl_xor(lossloc, m, 64);
    scoreloc += __shfl_xor(scoreloc, m, 64);
  }
  if (lane == 0) { redL[wave] = lossloc; redS[wave] = scoreloc; }
  __syncthreads();
  if (tid == 0) {
    atomicAdd(&accum[0], redL[0] + redL[1] + redL[2] + redL[3]);
    atomicAdd(&accum[1], redS[0] + redS[1] + redS[2] + redS[3]);
  }
}

__global__ void init_ws_kernel(float* ws) {
  ws[0] = 0.f;
  ws[1] = 0.f;
}

__global__ void finalize_kernel(const float* __restrict__ ws, float* __restrict__ out) {
  out[0] = (float)((double)ws[0] / ((double)BB * (double)CC));
  out[1] = (float)((double)ws[1] / (double)BB);
}

extern "C" void kernel_launch(void* const* d_in, const int* in_sizes, int n_in,
                              void* d_out, int out_size, void* d_ws, size_t ws_size,
                              hipStream_t stream) {
  const float* x  = (const float*)d_in[0];
  const float* y  = (const float*)d_in[1];
  const float* W  = (const float*)d_in[2];
  const float* b  = (const float*)d_in[3];
  const float* pw = (const float*)d_in[4];
  float* out = (float*)d_out;
  float* ws  = (float*)d_ws;

  hipLaunchKernelGGL(init_ws_kernel, dim3(1), dim3(1), 0, stream, ws);
  hipLaunchKernelGGL(fused_mfma_bce_topk, dim3(BB / BM), dim3(256), 0, stream,
                     x, y, W, b, pw, ws);
  hipLaunchKernelGGL(finalize_kernel, dim3(1), dim3(1), 0, stream, ws, out);
}

// Round 5
// 632.550 us; speedup vs baseline: 2.0395x; 1.0328x over previous
//
#include <hip/hip_runtime.h>
#include <math.h>

#define BB 32768
#define DD 512
#define CC 527
#define NT 33      // 33 n-tiles of 16 -> 528 padded cols (>= 527)
#define NCOL 528
#define BM 64      // rows per block (4 waves x 16 rows)
#define BK 32      // k-tile (one mfma K)
#define LDA 40     // LDS row stride in bf16 elems (80B)

typedef __attribute__((ext_vector_type(8))) short bf16x8;
typedef __attribute__((ext_vector_type(4))) float f32x4;

// Split accumulator: each alloca <= 288B so LLVM promotes to (A)VGPRs.
// (R2/R3 post-mortem: a single 528B f32x4[33] stayed in scratch -> 1.2GB
//  of scratch RMW traffic = the whole slowdown.)
#define ACC(t) ((t) < 17 ? acc0[(t)] : acc1[(t) - 17])

__device__ __forceinline__ short f2bf(float f) {  // fp32 -> bf16 RNE
  unsigned u = __float_as_uint(f);
  u += 0x7fffu + ((u >> 16) & 1u);
  return (short)(u >> 16);
}

__global__ __launch_bounds__(256, 2)
void fused_mfma_bce_topk(const float* __restrict__ x, const float* __restrict__ y,
                         const float* __restrict__ W, const float* __restrict__ bias,
                         const float* __restrict__ pw, float* __restrict__ accum) {
  __shared__ short As[BM * LDA];        // 5.0 KB
  __shared__ short Bs[NCOL * LDA];      // 41.25 KB
  __shared__ float redL[4], redS[4];

  const int tid  = threadIdx.x;
  const int wave = tid >> 6;
  const int lane = tid & 63;
  const int cl   = lane & 15;
  const int quad = lane >> 4;
  const int r0   = blockIdx.x * BM;

  f32x4 acc0[17], acc1[16];
#pragma unroll
  for (int t = 0; t < 17; ++t) acc0[t] = (f32x4){0.f, 0.f, 0.f, 0.f};
#pragma unroll
  for (int t = 0; t < 16; ++t) acc1[t] = (f32x4){0.f, 0.f, 0.f, 0.f};

  const int arow = tid >> 2, apos = tid & 3;

  // ---------------- MFMA GEMM over K = 512 ----------------
  for (int k0 = 0; k0 < DD; k0 += BK) {
    // Stage A: x[r0..r0+63][k0..k0+31] fp32 -> bf16 (non-temporal: streamed once)
    {
      const float* sA = x + (size_t)(r0 + arow) * DD + k0 + apos * 8;
      f32x4 f0 = __builtin_nontemporal_load((const f32x4*)sA);
      f32x4 f1 = __builtin_nontemporal_load((const f32x4*)(sA + 4));
      bf16x8 v;
      v[0]=f2bf(f0.x); v[1]=f2bf(f0.y); v[2]=f2bf(f0.z); v[3]=f2bf(f0.w);
      v[4]=f2bf(f1.x); v[5]=f2bf(f1.y); v[6]=f2bf(f1.z); v[7]=f2bf(f1.w);
      *(bf16x8*)(&As[arow * LDA + apos * 8]) = v;
    }
    // Stage B: W[0..526][k0..k0+31] fp32 -> bf16 (row 527 zero). Cached (reused).
#pragma unroll
    for (int i = 0; i < 9; ++i) {
      int ch = tid + i * 256;
      if (ch < NCOL * 4) {
        int row = ch >> 2, pos = ch & 3;
        short zz = 0;
        bf16x8 v = {zz, zz, zz, zz, zz, zz, zz, zz};
        if (row < CC) {
          const float* sB = W + (size_t)row * DD + k0 + pos * 8;
          f32x4 f0 = *(const f32x4*)sB;
          f32x4 f1 = *(const f32x4*)(sB + 4);
          v[0]=f2bf(f0.x); v[1]=f2bf(f0.y); v[2]=f2bf(f0.z); v[3]=f2bf(f0.w);
          v[4]=f2bf(f1.x); v[5]=f2bf(f1.y); v[6]=f2bf(f1.z); v[7]=f2bf(f1.w);
        }
        *(bf16x8*)(&Bs[row * LDA + pos * 8]) = v;
      }
    }
    __syncthreads();
    bf16x8 af = *(const bf16x8*)(&As[(wave * 16 + cl) * LDA + quad * 8]);
#pragma unroll
    for (int t = 0; t < NT; ++t) {
      bf16x8 bfr = *(const bf16x8*)(&Bs[(t * 16 + cl) * LDA + quad * 8]);
      ACC(t) = __builtin_amdgcn_mfma_f32_16x16x32_bf16(af, bfr, ACC(t), 0, 0, 0);
    }
    __syncthreads();
  }

  // ---------------- Epilogue (fragment-native, atomic-free) ----------------
  // C/D layout: col = t*16 + cl, row (within wave tile) = quad*4 + r
  const size_t growbase = (size_t)(r0 + wave * 16 + quad * 4);
  float lossloc = 0.f;
  unsigned long long ym[4] = {0ull, 0ull, 0ull, 0ull};

#pragma unroll
  for (int t = 0; t < NT; ++t) {
    int col = t * 16 + cl;
    bool cv = (col < CC);
    float bt = cv ? bias[col] : 0.f;
    float pt = cv ? pw[col]   : 1.f;
#pragma unroll
    for (int r = 0; r < 4; ++r) {
      float z = ACC(t)[r] + bt;
      if (cv) {
        float yv = __builtin_nontemporal_load(&y[(growbase + r) * CC + col]);
        float a  = fabsf(z);
        float l1 = log1pf(__expf(-a));
        float sp_pos = fmaxf(z, 0.f) + l1;   // softplus(z)
        float sp_neg = sp_pos - z;           // softplus(-z)
        lossloc += pt * yv * sp_neg + (1.f - yv) * sp_pos;
        if (yv > 0.5f) ym[r] |= (1ull << t);
        ACC(t)[r] = z;
      } else {
        ACC(t)[r] = -1e30f;   // exclude pad col from ranking
      }
    }
  }

  // k per row: popcount + 16-lane butterfly reduce, 2 rows packed per u32
  unsigned pk01 = (unsigned)__popcll(ym[0]) | ((unsigned)__popcll(ym[1]) << 16);
  unsigned pk23 = (unsigned)__popcll(ym[2]) | ((unsigned)__popcll(ym[3]) << 16);
#pragma unroll
  for (int m = 1; m <= 8; m <<= 1) {
    pk01 += __shfl_xor(pk01, m, 64);
    pk23 += __shfl_xor(pk23, m, 64);
  }
  const int kr[4] = {(int)(pk01 & 0xffffu), (int)(pk01 >> 16),
                     (int)(pk23 & 0xffffu), (int)(pk23 >> 16)};

  // Bisection: per-row threshold th with |{z > th}| == k
  float lo[4], hi[4], th[4];
  bool fnd[4];
#pragma unroll
  for (int r = 0; r < 4; ++r) { lo[r] = -1024.f; hi[r] = 1024.f; th[r] = 0.f; fnd[r] = false; }

  for (int it = 0; it < 48; ++it) {
    float tm[4];
#pragma unroll
    for (int r = 0; r < 4; ++r) tm[r] = 0.5f * (lo[r] + hi[r]);
    int c[4] = {0, 0, 0, 0};
#pragma unroll
    for (int t = 0; t < NT; ++t)
#pragma unroll
      for (int r = 0; r < 4; ++r) c[r] += (ACC(t)[r] > tm[r]) ? 1 : 0;
    unsigned p01 = (unsigned)c[0] | ((unsigned)c[1] << 16);
    unsigned p23 = (unsigned)c[2] | ((unsigned)c[3] << 16);
#pragma unroll
    for (int m = 1; m <= 8; m <<= 1) {
      p01 += __shfl_xor(p01, m, 64);
      p23 += __shfl_xor(p23, m, 64);
    }
    const int cc4[4] = {(int)(p01 & 0xffffu), (int)(p01 >> 16),
                        (int)(p23 & 0xffffu), (int)(p23 >> 16)};
    bool rem = false;
#pragma unroll
    for (int r = 0; r < 4; ++r) {
      if (!fnd[r]) {
        if (cc4[r] == kr[r])                        { th[r] = tm[r]; fnd[r] = true; }
        else if (tm[r] <= lo[r] || tm[r] >= hi[r])  { th[r] = lo[r]; fnd[r] = true; }
        else if (cc4[r] > kr[r])                    lo[r] = tm[r];
        else                                        hi[r] = tm[r];
      }
      rem |= !fnd[r];
    }
    if (__ballot(rem) == 0ull) break;
  }

  // hits = positives strictly above threshold
  int h[4] = {0, 0, 0, 0};
#pragma unroll
  for (int t = 0; t < NT; ++t)
#pragma unroll
    for (int r = 0; r < 4; ++r)
      if (((ym[r] >> t) & 1ull) && ACC(t)[r] > th[r]) h[r]++;
  unsigned q01 = (unsigned)h[0] | ((unsigned)h[1] << 16);
  unsigned q23 = (unsigned)h[2] | ((unsigned)h[3] << 16);
#pragma unroll
  for (int m = 1; m <= 8; m <<= 1) {
    q01 += __shfl_xor(q01, m, 64);
    q23 += __shfl_xor(q23, m, 64);
  }
  float scoreloc = 0.f;
  if (cl == 0) {
    const int hh[4] = {(int)(q01 & 0xffffu), (int)(q01 >> 16),
                       (int)(q23 & 0xffffu), (int)(q23 >> 16)};
#pragma unroll
    for (int r = 0; r < 4; ++r) scoreloc += (float)hh[r] / (float)kr[r];
  }

  // Block reduction -> one global atomic per block per output
#pragma unroll
  for (int m = 1; m < 64; m <<= 1) {
    lossloc  += __shfl_xor(lossloc, m, 64);
    scoreloc += __shfl_xor(scoreloc, m, 64);
  }
  if (lane == 0) { redL[wave] = lossloc; redS[wave] = scoreloc; }
  __syncthreads();
  if (tid == 0) {
    atomicAdd(&accum[0], redL[0] + redL[1] + redL[2] + redL[3]);
    atomicAdd(&accum[1], redS[0] + redS[1] + redS[2] + redS[3]);
  }
}

__global__ void init_ws_kernel(float* ws) {
  ws[0] = 0.f;
  ws[1] = 0.f;
}

__global__ void finalize_kernel(const float* __restrict__ ws, float* __restrict__ out) {
  out[0] = (float)((double)ws[0] / ((double)BB * (double)CC));
  out[1] = (float)((double)ws[1] / (double)BB);
}

extern "C" void kernel_launch(void* const* d_in, const int* in_sizes, int n_in,
                              void* d_out, int out_size, void* d_ws, size_t ws_size,
                              hipStream_t stream) {
  const float* x  = (const float*)d_in[0];
  const float* y  = (const float*)d_in[1];
  const float* W  = (const float*)d_in[2];
  const float* b  = (const float*)d_in[3];
  const float* pw = (const float*)d_in[4];
  float* out = (float*)d_out;
  float* ws  = (float*)d_ws;

  hipLaunchKernelGGL(init_ws_kernel, dim3(1), dim3(1), 0, stream, ws);
  hipLaunchKernelGGL(fused_mfma_bce_topk, dim3(BB / BM), dim3(256), 0, stream,
                     x, y, W, b, pw, ws);
  hipLaunchKernelGGL(finalize_kernel, dim3(1), dim3(1), 0, stream, ws, out);
}

// Round 6
// 354.388 us; speedup vs baseline: 3.6404x; 1.7849x over previous
//
#include <hip/hip_runtime.h>
#include <math.h>

#define BB 32768
#define DD 512
#define CC 527
#define NT 33      // 33 n-tiles of 16 -> 528 padded cols (>= 527)
#define NCOL 528
#define BM 64      // rows per block (4 waves x 16 rows)
#define BK 32      // k-tile (one mfma K)
#define LDA 40     // LDS row stride in bf16 elems (80B)

typedef __attribute__((ext_vector_type(8))) short bf16x8;
typedef __attribute__((ext_vector_type(4))) float f32x4;

// R2-R5 post-mortem: f32x4 acc arrays (528B, even split 272B+256B) are NEVER
// SROA-promoted by this toolchain -> scratch RMW = 1.2GB HBM writes = 543us.
// Fix: 33 NAMED f32x4 SSA variables via X-macro. Named locals can't be allocas.
#define FOREACH_T(OP) \
  OP(0) OP(1) OP(2) OP(3) OP(4) OP(5) OP(6) OP(7) OP(8) OP(9) OP(10) OP(11) \
  OP(12) OP(13) OP(14) OP(15) OP(16) OP(17) OP(18) OP(19) OP(20) OP(21) \
  OP(22) OP(23) OP(24) OP(25) OP(26) OP(27) OP(28) OP(29) OP(30) OP(31) OP(32)

__device__ __forceinline__ short f2bf(float f) {  // fp32 -> bf16 RNE
  unsigned u = __float_as_uint(f);
  u += 0x7fffu + ((u >> 16) & 1u);
  return (short)(u >> 16);
}

__global__ __launch_bounds__(256, 2)
void fused_mfma_bce_topk(const float* __restrict__ x, const float* __restrict__ y,
                         const float* __restrict__ W, const float* __restrict__ bias,
                         const float* __restrict__ pw, float* __restrict__ accum) {
  __shared__ short As[BM * LDA];        // 5.0 KB
  __shared__ short Bs[NCOL * LDA];      // 41.25 KB
  __shared__ float redL[4], redS[4];

  const int tid  = threadIdx.x;
  const int wave = tid >> 6;
  const int lane = tid & 63;
  const int cl   = lane & 15;
  const int quad = lane >> 4;
  const int r0   = blockIdx.x * BM;

#define DECL_ACC(t) f32x4 A##t = (f32x4){0.f, 0.f, 0.f, 0.f};
  FOREACH_T(DECL_ACC)
#undef DECL_ACC

  const int arow = tid >> 2, apos = tid & 3;

  // ---------------- MFMA GEMM over K = 512 ----------------
  for (int k0 = 0; k0 < DD; k0 += BK) {
    // Stage A: x[r0..r0+63][k0..k0+31] fp32 -> bf16 (non-temporal: streamed once)
    {
      const float* sA = x + (size_t)(r0 + arow) * DD + k0 + apos * 8;
      f32x4 f0 = __builtin_nontemporal_load((const f32x4*)sA);
      f32x4 f1 = __builtin_nontemporal_load((const f32x4*)(sA + 4));
      bf16x8 v;
      v[0]=f2bf(f0.x); v[1]=f2bf(f0.y); v[2]=f2bf(f0.z); v[3]=f2bf(f0.w);
      v[4]=f2bf(f1.x); v[5]=f2bf(f1.y); v[6]=f2bf(f1.z); v[7]=f2bf(f1.w);
      *(bf16x8*)(&As[arow * LDA + apos * 8]) = v;
    }
    // Stage B: W[0..526][k0..k0+31] fp32 -> bf16 (row 527 zero). Cached (reused).
#pragma unroll
    for (int i = 0; i < 9; ++i) {
      int ch = tid + i * 256;
      if (ch < NCOL * 4) {
        int row = ch >> 2, pos = ch & 3;
        short zz = 0;
        bf16x8 v = {zz, zz, zz, zz, zz, zz, zz, zz};
        if (row < CC) {
          const float* sB = W + (size_t)row * DD + k0 + pos * 8;
          f32x4 f0 = *(const f32x4*)sB;
          f32x4 f1 = *(const f32x4*)(sB + 4);
          v[0]=f2bf(f0.x); v[1]=f2bf(f0.y); v[2]=f2bf(f0.z); v[3]=f2bf(f0.w);
          v[4]=f2bf(f1.x); v[5]=f2bf(f1.y); v[6]=f2bf(f1.z); v[7]=f2bf(f1.w);
        }
        *(bf16x8*)(&Bs[row * LDA + pos * 8]) = v;
      }
    }
    __syncthreads();
    {
      bf16x8 af = *(const bf16x8*)(&As[(wave * 16 + cl) * LDA + quad * 8]);
#define MFSTEP(t) { \
      bf16x8 bfr = *(const bf16x8*)(&Bs[((t) * 16 + cl) * LDA + quad * 8]); \
      A##t = __builtin_amdgcn_mfma_f32_16x16x32_bf16(af, bfr, A##t, 0, 0, 0); }
      FOREACH_T(MFSTEP)
#undef MFSTEP
    }
    __syncthreads();
  }

  // ---------------- Epilogue (fragment-native, atomic-free) ----------------
  // C/D layout: col = t*16 + cl, row (within wave tile) = quad*4 + r
  const size_t growbase = (size_t)(r0 + wave * 16 + quad * 4);
  float lossloc = 0.f;
  unsigned long long ym[4] = {0ull, 0ull, 0ull, 0ull};

#define EPI(t) { \
    int col = (t) * 16 + cl; \
    bool cv = (col < CC); \
    float bt = cv ? bias[col] : 0.f; \
    float pt = cv ? pw[col]   : 1.f; \
    _Pragma("unroll") \
    for (int r = 0; r < 4; ++r) { \
      float z = A##t[r] + bt; \
      if (cv) { \
        float yv = __builtin_nontemporal_load(&y[(growbase + r) * CC + col]); \
        float a  = fabsf(z); \
        float l1 = log1pf(__expf(-a)); \
        float sp_pos = fmaxf(z, 0.f) + l1; \
        float sp_neg = sp_pos - z; \
        lossloc += pt * yv * sp_neg + (1.f - yv) * sp_pos; \
        if (yv > 0.5f) ym[r] |= (1ull << (t)); \
        A##t[r] = z; \
      } else { \
        A##t[r] = -1e30f; \
      } \
    } }
  FOREACH_T(EPI)
#undef EPI

  // k per row: popcount + 16-lane butterfly reduce, 2 rows packed per u32
  unsigned pk01 = (unsigned)__popcll(ym[0]) | ((unsigned)__popcll(ym[1]) << 16);
  unsigned pk23 = (unsigned)__popcll(ym[2]) | ((unsigned)__popcll(ym[3]) << 16);
#pragma unroll
  for (int m = 1; m <= 8; m <<= 1) {
    pk01 += __shfl_xor(pk01, m, 64);
    pk23 += __shfl_xor(pk23, m, 64);
  }
  const int kr[4] = {(int)(pk01 & 0xffffu), (int)(pk01 >> 16),
                     (int)(pk23 & 0xffffu), (int)(pk23 >> 16)};

  // Bisection: per-row threshold th with |{z > th}| == k
  float lo[4], hi[4], th[4];
  bool fnd[4];
#pragma unroll
  for (int r = 0; r < 4; ++r) { lo[r] = -1024.f; hi[r] = 1024.f; th[r] = 0.f; fnd[r] = false; }

  for (int it = 0; it < 48; ++it) {
    float tm[4];
#pragma unroll
    for (int r = 0; r < 4; ++r) tm[r] = 0.5f * (lo[r] + hi[r]);
    int c[4] = {0, 0, 0, 0};
#define CNT(t) { \
    _Pragma("unroll") \
    for (int r = 0; r < 4; ++r) c[r] += (A##t[r] > tm[r]) ? 1 : 0; }
    FOREACH_T(CNT)
#undef CNT
    unsigned p01 = (unsigned)c[0] | ((unsigned)c[1] << 16);
    unsigned p23 = (unsigned)c[2] | ((unsigned)c[3] << 16);
#pragma unroll
    for (int m = 1; m <= 8; m <<= 1) {
      p01 += __shfl_xor(p01, m, 64);
      p23 += __shfl_xor(p23, m, 64);
    }
    const int cc4[4] = {(int)(p01 & 0xffffu), (int)(p01 >> 16),
                        (int)(p23 & 0xffffu), (int)(p23 >> 16)};
    bool rem = false;
#pragma unroll
    for (int r = 0; r < 4; ++r) {
      if (!fnd[r]) {
        if (cc4[r] == kr[r])                        { th[r] = tm[r]; fnd[r] = true; }
        else if (tm[r] <= lo[r] || tm[r] >= hi[r])  { th[r] = lo[r]; fnd[r] = true; }
        else if (cc4[r] > kr[r])                    lo[r] = tm[r];
        else                                        hi[r] = tm[r];
      }
      rem |= !fnd[r];
    }
    if (__ballot(rem) == 0ull) break;
  }

  // hits = positives strictly above threshold
  int h[4] = {0, 0, 0, 0};
#define HIT(t) { \
    _Pragma("unroll") \
    for (int r = 0; r < 4; ++r) \
      if (((ym[r] >> (t)) & 1ull) && A##t[r] > th[r]) h[r]++; }
  FOREACH_T(HIT)
#undef HIT
  unsigned q01 = (unsigned)h[0] | ((unsigned)h[1] << 16);
  unsigned q23 = (unsigned)h[2] | ((unsigned)h[3] << 16);
#pragma unroll
  for (int m = 1; m <= 8; m <<= 1) {
    q01 += __shfl_xor(q01, m, 64);
    q23 += __shfl_xor(q23, m, 64);
  }
  float scoreloc = 0.f;
  if (cl == 0) {
    const int hh[4] = {(int)(q01 & 0xffffu), (int)(q01 >> 16),
                       (int)(q23 & 0xffffu), (int)(q23 >> 16)};
#pragma unroll
    for (int r = 0; r < 4; ++r) scoreloc += (float)hh[r] / (float)kr[r];
  }

  // Block reduction -> one global atomic per block per output
#pragma unroll
  for (int m = 1; m < 64; m <<= 1) {
    lossloc  += __shfl_xor(lossloc, m, 64);
    scoreloc += __shfl_xor(scoreloc, m, 64);
  }
  if (lane == 0) { redL[wave] = lossloc; redS[wave] = scoreloc; }
  __syncthreads();
  if (tid == 0) {
    atomicAdd(&accum[0], redL[0] + redL[1] + redL[2] + redL[3]);
    atomicAdd(&accum[1], redS[0] + redS[1] + redS[2] + redS[3]);
  }
}

__global__ void init_ws_kernel(float* ws) {
  ws[0] = 0.f;
  ws[1] = 0.f;
}

__global__ void finalize_kernel(const float* __restrict__ ws, float* __restrict__ out) {
  out[0] = (float)((double)ws[0] / ((double)BB * (double)CC));
  out[1] = (float)((double)ws[1] / (double)BB);
}

extern "C" void kernel_launch(void* const* d_in, const int* in_sizes, int n_in,
                              void* d_out, int out_size, void* d_ws, size_t ws_size,
                              hipStream_t stream) {
  const float* x  = (const float*)d_in[0];
  const float* y  = (const float*)d_in[1];
  const float* W  = (const float*)d_in[2];
  const float* b  = (const float*)d_in[3];
  const float* pw = (const float*)d_in[4];
  float* out = (float*)d_out;
  float* ws  = (float*)d_ws;

  hipLaunchKernelGGL(init_ws_kernel, dim3(1), dim3(1), 0, stream, ws);
  hipLaunchKernelGGL(fused_mfma_bce_topk, dim3(BB / BM), dim3(256), 0, stream,
                     x, y, W, b, pw, ws);
  hipLaunchKernelGGL(finalize_kernel, dim3(1), dim3(1), 0, stream, ws, out);
}